// Round 1
// baseline (2667.994 us; speedup 1.0000x reference)
//
#include <hip/hip_runtime.h>
#include <hip/hip_bf16.h>

#define HD 14   // hidden dim
#define NOUT 2

__device__ __forceinline__ float psi_f(float v) {
    float r = log1pf(fabsf(v));
    return v < 0.f ? -r : r;
}

__device__ __forceinline__ void stage_f(float* dst, const float* src, int n) {
    for (int i = threadIdx.x; i < n; i += blockDim.x) dst[i] = src[i];
}

// ---------------- Edge kernel ----------------
// Per edge: build Lorentz-invariant features, edge MLP (4->H->H),
// node_mlp_1 (1+H -> H -> H), scatter-add m into aggsum[col], cnt[col]++.
__global__ void __launch_bounds__(256)
edge_kernel(const float4* __restrict__ x,
            const int* __restrict__ row, const int* __restrict__ col,
            const float* __restrict__ We1, const float* __restrict__ be1,
            const float* __restrict__ We2, const float* __restrict__ be2,
            const float* __restrict__ Wn11, const float* __restrict__ bn11,
            const float* __restrict__ Wn12, const float* __restrict__ bn12,
            float* __restrict__ aggsum, int* __restrict__ cnt, int E)
{
    __shared__ float sWe1[4*HD], sbe1[HD], sWe2[HD*HD], sbe2[HD];
    __shared__ float sWn11[(1+HD)*HD], sbn11[HD], sWn12[HD*HD], sbn12[HD];
    stage_f(sWe1, We1, 4*HD);   stage_f(sbe1, be1, HD);
    stage_f(sWe2, We2, HD*HD);  stage_f(sbe2, be2, HD);
    stage_f(sWn11, Wn11, (1+HD)*HD); stage_f(sbn11, bn11, HD);
    stage_f(sWn12, Wn12, HD*HD); stage_f(sbn12, bn12, HD);
    __syncthreads();

    int e = blockIdx.x * blockDim.x + threadIdx.x;
    if (e >= E) return;

    int r = row[e];
    int c = col[e];
    float4 a = x[r];
    float4 b = x[c];

    // Minkowski metric diag(-1,1,1,1)
    float f0 = -a.x*a.x + a.y*a.y + a.z*a.z + a.w*a.w;         // ip(src,src)
    float f1 = -a.x*b.x + a.y*b.y + a.z*b.z + a.w*b.w;         // ip(src,dst)
    float ipbb = -b.x*b.x + b.y*b.y + b.z*b.z + b.w*b.w;
    float dx = a.x-b.x, dy = a.y-b.y, dz = a.z-b.z, dw = a.w-b.w;
    float ipdd = -dx*dx + dy*dy + dz*dz + dw*dw;
    float f2 = psi_f(ipbb);
    float f3 = psi_f(ipdd);

    // edge MLP layer 1: 4 -> H, relu
    float h1[HD];
    #pragma unroll
    for (int j = 0; j < HD; ++j) {
        float v = f0*sWe1[0*HD+j] + f1*sWe1[1*HD+j] + f2*sWe1[2*HD+j] + f3*sWe1[3*HD+j] + sbe1[j];
        h1[j] = fmaxf(v, 0.f);
    }
    // edge MLP layer 2: H -> H  (edge_attr)
    float ea[HD];
    #pragma unroll
    for (int j = 0; j < HD; ++j) {
        float v = sbe2[j];
        #pragma unroll
        for (int k = 0; k < HD; ++k) v = fmaf(h1[k], sWe2[k*HD+j], v);
        ea[j] = v;
    }
    // node_mlp_1 layer 1: [ip_ss, edge_attr] (15) -> H, relu
    float h2[HD];
    #pragma unroll
    for (int j = 0; j < HD; ++j) {
        float v = fmaf(f0, sWn11[0*HD+j], sbn11[j]);
        #pragma unroll
        for (int k = 0; k < HD; ++k) v = fmaf(ea[k], sWn11[(1+k)*HD+j], v);
        h2[j] = fmaxf(v, 0.f);
    }
    // node_mlp_1 layer 2: H -> H, scatter into aggsum[col]
    float* dstp = aggsum + (size_t)c * HD;
    #pragma unroll
    for (int j = 0; j < HD; ++j) {
        float v = sbn12[j];
        #pragma unroll
        for (int k = 0; k < HD; ++k) v = fmaf(h2[k], sWn12[k*HD+j], v);
        atomicAdd(dstp + j, v);
    }
    atomicAdd(cnt + c, 1);
}

// ---------------- Node kernel ----------------
// Per node: agg = aggsum/max(cnt,1); x_out = node_mlp_2([ip(x,x), agg]);
// scatter-add into gsum[batch], gcnt[batch]++.
__global__ void __launch_bounds__(256)
node_kernel(const float4* __restrict__ x,
            const float* __restrict__ aggsum, const int* __restrict__ cnt,
            const int* __restrict__ batch,
            const float* __restrict__ Wn21, const float* __restrict__ bn21,
            const float* __restrict__ Wn22, const float* __restrict__ bn22,
            float* __restrict__ gsum, int* __restrict__ gcnt, int N)
{
    __shared__ float sW1[(1+HD)*HD], sb1[HD], sW2[HD*HD], sb2[HD];
    stage_f(sW1, Wn21, (1+HD)*HD); stage_f(sb1, bn21, HD);
    stage_f(sW2, Wn22, HD*HD);     stage_f(sb2, bn22, HD);
    __syncthreads();

    int n = blockIdx.x * blockDim.x + threadIdx.x;
    if (n >= N) return;

    float4 a = x[n];
    float ipxx = -a.x*a.x + a.y*a.y + a.z*a.z + a.w*a.w;

    float invc = 1.0f / fmaxf((float)cnt[n], 1.0f);
    const float* ap = aggsum + (size_t)n * HD;
    float agg[HD];
    #pragma unroll
    for (int j = 0; j < HD; ++j) agg[j] = ap[j] * invc;

    float h[HD];
    #pragma unroll
    for (int j = 0; j < HD; ++j) {
        float v = fmaf(ipxx, sW1[0*HD+j], sb1[j]);
        #pragma unroll
        for (int k = 0; k < HD; ++k) v = fmaf(agg[k], sW1[(1+k)*HD+j], v);
        h[j] = fmaxf(v, 0.f);
    }
    int b = batch[n];
    float* gp = gsum + (size_t)b * HD;
    #pragma unroll
    for (int j = 0; j < HD; ++j) {
        float v = sb2[j];
        #pragma unroll
        for (int k = 0; k < HD; ++k) v = fmaf(h[k], sW2[k*HD+j], v);
        atomicAdd(gp + j, v);
    }
    atomicAdd(gcnt + b, 1);
}

// ---------------- Global kernel ----------------
__global__ void __launch_bounds__(256)
global_kernel(const float* __restrict__ gsum, const int* __restrict__ gcnt,
              const float* __restrict__ Wg1, const float* __restrict__ bg1,
              const float* __restrict__ Wg2, const float* __restrict__ bg2,
              float* __restrict__ out, int G)
{
    int g = blockIdx.x * blockDim.x + threadIdx.x;
    if (g >= G) return;
    float invc = 1.0f / fmaxf((float)gcnt[g], 1.0f);
    const float* gp = gsum + (size_t)g * HD;
    float gm[HD];
    #pragma unroll
    for (int j = 0; j < HD; ++j) gm[j] = gp[j] * invc;

    float h[HD];
    #pragma unroll
    for (int j = 0; j < HD; ++j) {
        float v = bg1[j];
        #pragma unroll
        for (int k = 0; k < HD; ++k) v = fmaf(gm[k], Wg1[k*HD+j], v);
        h[j] = fmaxf(v, 0.f);
    }
    #pragma unroll
    for (int o = 0; o < NOUT; ++o) {
        float v = bg2[o];
        #pragma unroll
        for (int k = 0; k < HD; ++k) v = fmaf(h[k], Wg2[k*NOUT+o], v);
        out[g*NOUT + o] = v;
    }
}

extern "C" void kernel_launch(void* const* d_in, const int* in_sizes, int n_in,
                              void* d_out, int out_size, void* d_ws, size_t ws_size,
                              hipStream_t stream) {
    const int N = 200000;
    const int E = 3200000;
    const int G = 2000;

    const float4* x       = (const float4*)d_in[0];
    const int*    eidx    = (const int*)d_in[1];
    const int*    batch   = (const int*)d_in[2];
    const float*  We1  = (const float*)d_in[3];
    const float*  be1  = (const float*)d_in[4];
    const float*  We2  = (const float*)d_in[5];
    const float*  be2  = (const float*)d_in[6];
    const float*  Wn11 = (const float*)d_in[7];
    const float*  bn11 = (const float*)d_in[8];
    const float*  Wn12 = (const float*)d_in[9];
    const float*  bn12 = (const float*)d_in[10];
    const float*  Wn21 = (const float*)d_in[11];
    const float*  bn21 = (const float*)d_in[12];
    const float*  Wn22 = (const float*)d_in[13];
    const float*  bn22 = (const float*)d_in[14];
    const float*  Wg1  = (const float*)d_in[15];
    const float*  bg1  = (const float*)d_in[16];
    const float*  Wg2  = (const float*)d_in[17];
    const float*  bg2  = (const float*)d_in[18];

    const int* row = eidx;          // edge_index[0]
    const int* col = eidx + E;      // edge_index[1]

    // workspace layout (bytes):
    // [0, 11200000)            aggsum  N*HD floats
    // [11200000, 12000000)     cnt     N ints
    // [12000000, 12112000)     gsum    G*HD floats
    // [12112000, 12120000)     gcnt    G ints
    char* ws = (char*)d_ws;
    float* aggsum = (float*)(ws + 0);
    int*   cnt    = (int*)  (ws + 11200000);
    float* gsum   = (float*)(ws + 12000000);
    int*   gcnt   = (int*)  (ws + 12112000);

    hipMemsetAsync(d_ws, 0, 12120000, stream);

    dim3 blk(256);
    dim3 grid_e((E + 255) / 256);
    edge_kernel<<<grid_e, blk, 0, stream>>>(x, row, col, We1, be1, We2, be2,
                                            Wn11, bn11, Wn12, bn12,
                                            aggsum, cnt, E);

    dim3 grid_n((N + 255) / 256);
    node_kernel<<<grid_n, blk, 0, stream>>>(x, aggsum, cnt, batch,
                                            Wn21, bn21, Wn22, bn22,
                                            gsum, gcnt, N);

    dim3 grid_g((G + 255) / 256);
    global_kernel<<<grid_g, blk, 0, stream>>>(gsum, gcnt, Wg1, bg1, Wg2, bg2,
                                              (float*)d_out, G);
}

// Round 2
// 1586.781 us; speedup vs baseline: 1.6814x; 1.6814x over previous
//
#include <hip/hip_runtime.h>
#include <hip/hip_bf16.h>

#define HD 14
#define NOUT 2
#define NN 200000
#define EE 3200000
#define GG 2000

// scan config
#define SBS 256
#define SEL 8
#define CHUNK (SBS*SEL)                 // 2048
#define NB1 ((NN + CHUNK - 1) / CHUNK)  // 98

__device__ __forceinline__ float psi_f(float v) {
    float r = log1pf(fabsf(v));
    return v < 0.f ? -r : r;
}

__device__ __forceinline__ void stage_f(float* dst, const float* src, int n) {
    for (int i = threadIdx.x; i < n; i += blockDim.x) dst[i] = src[i];
}

__device__ __forceinline__ int lower_bound_i(const int* a, int n, int key) {
    int lo = 0, hi = n;
    while (lo < hi) { int mid = (lo + hi) >> 1; if (a[mid] < key) lo = mid + 1; else hi = mid; }
    return lo;
}

// ---- pass 1: per-edge rank within destination node (the only atomic pass) ----
__global__ void __launch_bounds__(256)
rank_kernel(const int* __restrict__ col, int* __restrict__ cnt,
            int* __restrict__ rank, int E)
{
    int e = blockIdx.x * 256 + threadIdx.x;
    if (e >= E) return;
    rank[e] = atomicAdd(&cnt[col[e]], 1);
}

// ---- exclusive scan of cnt[N] -> offsets[N] (3 kernels) ----
__global__ void __launch_bounds__(SBS)
scan1_kernel(const int* __restrict__ cnt, int* __restrict__ excl,
             int* __restrict__ btot, int n)
{
    __shared__ int lds[SBS];
    int tid = threadIdx.x;
    int base = blockIdx.x * CHUNK + tid * SEL;
    int v[SEL]; int s = 0;
    #pragma unroll
    for (int k = 0; k < SEL; ++k) { int i = base + k; v[k] = (i < n) ? cnt[i] : 0; s += v[k]; }
    lds[tid] = s; __syncthreads();
    for (int off = 1; off < SBS; off <<= 1) {
        int t = (tid >= off) ? lds[tid - off] : 0;
        __syncthreads();
        lds[tid] += t;
        __syncthreads();
    }
    int incl = lds[tid];
    int run = incl - s;                       // exclusive base for this thread
    if (tid == SBS - 1) btot[blockIdx.x] = incl;
    #pragma unroll
    for (int k = 0; k < SEL; ++k) { int i = base + k; if (i < n) excl[i] = run; run += v[k]; }
}

__global__ void __launch_bounds__(128)
scan2_kernel(int* __restrict__ btot, int* __restrict__ total_out, int nb)
{
    __shared__ int lds[128];
    int tid = threadIdx.x;
    int v = (tid < nb) ? btot[tid] : 0;
    lds[tid] = v; __syncthreads();
    for (int off = 1; off < 128; off <<= 1) {
        int t = (tid >= off) ? lds[tid - off] : 0;
        __syncthreads();
        lds[tid] += t;
        __syncthreads();
    }
    if (tid < nb) btot[tid] = lds[tid] - v;   // exclusive block bases (in place)
    if (tid == 127) *total_out = lds[127];    // = E, stored as offsets[N]
}

__global__ void __launch_bounds__(SBS)
scan3_kernel(int* __restrict__ excl, const int* __restrict__ btot, int n)
{
    int b = btot[blockIdx.x];
    int base = blockIdx.x * CHUNK + threadIdx.x * SEL;
    #pragma unroll
    for (int k = 0; k < SEL; ++k) { int i = base + k; if (i < n) excl[i] += b; }
}

// ---- pass 2: atomic-free scatter of edge ids into col-sorted order ----
__global__ void __launch_bounds__(256)
scatter_kernel(const int* __restrict__ col, const int* __restrict__ rank,
               const int* __restrict__ offsets, int* __restrict__ eids, int E)
{
    int e = blockIdx.x * 256 + threadIdx.x;
    if (e >= E) return;
    eids[offsets[col[e]] + rank[e]] = e;
}

// ---- pass 3: per-node edge recompute + aggregate + node MLP ----
__global__ void __launch_bounds__(256)
node_kernel(const float4* __restrict__ x,
            const int* __restrict__ row, const int* __restrict__ eids,
            const int* __restrict__ offsets,
            const float* __restrict__ We1, const float* __restrict__ be1,
            const float* __restrict__ We2, const float* __restrict__ be2,
            const float* __restrict__ Wn11, const float* __restrict__ bn11,
            const float* __restrict__ Wn12, const float* __restrict__ bn12,
            const float* __restrict__ Wn21, const float* __restrict__ bn21,
            const float* __restrict__ Wn22, const float* __restrict__ bn22,
            float* __restrict__ x_out, int N)
{
    __shared__ float sWe1[4*HD], sbe1[HD], sWe2[HD*HD], sbe2[HD];
    __shared__ float sWn11[(1+HD)*HD], sbn11[HD], sWn12[HD*HD], sbn12[HD];
    __shared__ float sWn21[(1+HD)*HD], sbn21[HD], sWn22[HD*HD], sbn22[HD];
    stage_f(sWe1, We1, 4*HD);        stage_f(sbe1, be1, HD);
    stage_f(sWe2, We2, HD*HD);       stage_f(sbe2, be2, HD);
    stage_f(sWn11, Wn11, (1+HD)*HD); stage_f(sbn11, bn11, HD);
    stage_f(sWn12, Wn12, HD*HD);     stage_f(sbn12, bn12, HD);
    stage_f(sWn21, Wn21, (1+HD)*HD); stage_f(sbn21, bn21, HD);
    stage_f(sWn22, Wn22, HD*HD);     stage_f(sbn22, bn22, HD);
    __syncthreads();

    int n = blockIdx.x * 256 + threadIdx.x;
    if (n >= N) return;

    float4 b = x[n];                                  // dst for all its edges
    float ipbb = -b.x*b.x + b.y*b.y + b.z*b.z + b.w*b.w;
    float f2 = psi_f(ipbb);                           // constant per node

    int lo = offsets[n], hi = offsets[n + 1];
    int deg = hi - lo;

    float agg[HD];
    #pragma unroll
    for (int j = 0; j < HD; ++j) agg[j] = 0.f;

    for (int i = lo; i < hi; ++i) {
        int e = eids[i];
        int r = row[e];
        float4 a = x[r];                              // src

        float f0 = -a.x*a.x + a.y*a.y + a.z*a.z + a.w*a.w;
        float f1 = -a.x*b.x + a.y*b.y + a.z*b.z + a.w*b.w;
        float dx = a.x-b.x, dy = a.y-b.y, dz = a.z-b.z, dw = a.w-b.w;
        float f3 = psi_f(-dx*dx + dy*dy + dz*dz + dw*dw);

        float h1[HD];
        #pragma unroll
        for (int j = 0; j < HD; ++j) {
            float v = f0*sWe1[0*HD+j] + f1*sWe1[1*HD+j] + f2*sWe1[2*HD+j] + f3*sWe1[3*HD+j] + sbe1[j];
            h1[j] = fmaxf(v, 0.f);
        }
        float ea[HD];
        #pragma unroll
        for (int j = 0; j < HD; ++j) {
            float v = sbe2[j];
            #pragma unroll
            for (int k = 0; k < HD; ++k) v = fmaf(h1[k], sWe2[k*HD+j], v);
            ea[j] = v;
        }
        float h2[HD];
        #pragma unroll
        for (int j = 0; j < HD; ++j) {
            float v = fmaf(f0, sWn11[0*HD+j], sbn11[j]);
            #pragma unroll
            for (int k = 0; k < HD; ++k) v = fmaf(ea[k], sWn11[(1+k)*HD+j], v);
            h2[j] = fmaxf(v, 0.f);
        }
        #pragma unroll
        for (int j = 0; j < HD; ++j) {
            float v = sbn12[j];
            #pragma unroll
            for (int k = 0; k < HD; ++k) v = fmaf(h2[k], sWn12[k*HD+j], v);
            agg[j] += v;
        }
    }

    float invc = 1.0f / fmaxf((float)deg, 1.0f);
    #pragma unroll
    for (int j = 0; j < HD; ++j) agg[j] *= invc;

    float h[HD];
    #pragma unroll
    for (int j = 0; j < HD; ++j) {
        float v = fmaf(ipbb, sWn21[0*HD+j], sbn21[j]);
        #pragma unroll
        for (int k = 0; k < HD; ++k) v = fmaf(agg[k], sWn21[(1+k)*HD+j], v);
        h[j] = fmaxf(v, 0.f);
    }
    float xo[16];
    #pragma unroll
    for (int j = 0; j < HD; ++j) {
        float v = sbn22[j];
        #pragma unroll
        for (int k = 0; k < HD; ++k) v = fmaf(h[k], sWn22[k*HD+j], v);
        xo[j] = v;
    }
    xo[14] = 0.f; xo[15] = 0.f;

    float4* op = (float4*)(x_out + (size_t)n * 16);
    op[0] = make_float4(xo[0], xo[1], xo[2], xo[3]);
    op[1] = make_float4(xo[4], xo[5], xo[6], xo[7]);
    op[2] = make_float4(xo[8], xo[9], xo[10], xo[11]);
    op[3] = make_float4(xo[12], xo[13], xo[14], xo[15]);
}

// ---- pass 4: per-graph mean (batch is sorted -> contiguous ranges) + global MLP ----
__global__ void __launch_bounds__(256)
graph_kernel(const float* __restrict__ x_out, const int* __restrict__ batch,
             const float* __restrict__ Wg1, const float* __restrict__ bg1,
             const float* __restrict__ Wg2, const float* __restrict__ bg2,
             float* __restrict__ out, int N, int G)
{
    __shared__ float red[256 * 15];
    int g = blockIdx.x;
    int tid = threadIdx.x;

    int lo = lower_bound_i(batch, N, g);
    int hi = lower_bound_i(batch, N, g + 1);

    float acc[HD];
    #pragma unroll
    for (int j = 0; j < HD; ++j) acc[j] = 0.f;

    for (int n = lo + tid; n < hi; n += 256) {
        const float* xp = x_out + (size_t)n * 16;
        #pragma unroll
        for (int j = 0; j < HD; ++j) acc[j] += xp[j];
    }
    #pragma unroll
    for (int j = 0; j < HD; ++j) red[tid * 15 + j] = acc[j];
    __syncthreads();

    for (int s = 128; s >= 1; s >>= 1) {
        if (tid < s) {
            #pragma unroll
            for (int j = 0; j < HD; ++j) red[tid * 15 + j] += red[(tid + s) * 15 + j];
        }
        __syncthreads();
    }

    if (tid == 0) {
        float invc = 1.0f / fmaxf((float)(hi - lo), 1.0f);
        float gm[HD];
        #pragma unroll
        for (int j = 0; j < HD; ++j) gm[j] = red[j] * invc;
        float h[HD];
        #pragma unroll
        for (int j = 0; j < HD; ++j) {
            float v = bg1[j];
            #pragma unroll
            for (int k = 0; k < HD; ++k) v = fmaf(gm[k], Wg1[k*HD+j], v);
            h[j] = fmaxf(v, 0.f);
        }
        #pragma unroll
        for (int o = 0; o < NOUT; ++o) {
            float v = bg2[o];
            #pragma unroll
            for (int k = 0; k < HD; ++k) v = fmaf(h[k], Wg2[k*NOUT+o], v);
            out[g * NOUT + o] = v;
        }
    }
}

extern "C" void kernel_launch(void* const* d_in, const int* in_sizes, int n_in,
                              void* d_out, int out_size, void* d_ws, size_t ws_size,
                              hipStream_t stream) {
    const int N = NN, E = EE, G = GG;

    const float4* x     = (const float4*)d_in[0];
    const int*    eidx  = (const int*)d_in[1];
    const int*    batch = (const int*)d_in[2];
    const float*  We1  = (const float*)d_in[3];
    const float*  be1  = (const float*)d_in[4];
    const float*  We2  = (const float*)d_in[5];
    const float*  be2  = (const float*)d_in[6];
    const float*  Wn11 = (const float*)d_in[7];
    const float*  bn11 = (const float*)d_in[8];
    const float*  Wn12 = (const float*)d_in[9];
    const float*  bn12 = (const float*)d_in[10];
    const float*  Wn21 = (const float*)d_in[11];
    const float*  bn21 = (const float*)d_in[12];
    const float*  Wn22 = (const float*)d_in[13];
    const float*  bn22 = (const float*)d_in[14];
    const float*  Wg1  = (const float*)d_in[15];
    const float*  bg1  = (const float*)d_in[16];
    const float*  Wg2  = (const float*)d_in[17];
    const float*  bg2  = (const float*)d_in[18];

    const int* row = eidx;       // edge_index[0]
    const int* col = eidx + E;   // edge_index[1]

    // workspace layout (bytes), all 256-aligned:
    //   [0,        800000)    cnt      N ints  (must be zeroed)
    //   [800000,  13600000)   rank     E ints
    //   [13600000,14400256)   offsets  N+1 ints
    //   [14400256,14400768)   btot     NB1 ints (scan block sums)
    //   [14400768,27200768)   eids     E ints (col-sorted edge ids)
    //   [27200768,40000768)   x_out    N*16 floats (padded rows)
    char* ws = (char*)d_ws;
    int*   cnt     = (int*)(ws + 0);
    int*   rank    = (int*)(ws + 800000);
    int*   offsets = (int*)(ws + 13600000);
    int*   btot    = (int*)(ws + 14400256);
    int*   eids    = (int*)(ws + 14400768);
    float* x_out   = (float*)(ws + 27200768);

    hipMemsetAsync(cnt, 0, (size_t)N * sizeof(int), stream);

    dim3 blk(256);
    rank_kernel<<<dim3((E + 255) / 256), blk, 0, stream>>>(col, cnt, rank, E);

    scan1_kernel<<<dim3(NB1), dim3(SBS), 0, stream>>>(cnt, offsets, btot, N);
    scan2_kernel<<<dim3(1), dim3(128), 0, stream>>>(btot, offsets + N, NB1);
    scan3_kernel<<<dim3(NB1), dim3(SBS), 0, stream>>>(offsets, btot, N);

    scatter_kernel<<<dim3((E + 255) / 256), blk, 0, stream>>>(col, rank, offsets, eids, E);

    node_kernel<<<dim3((N + 255) / 256), blk, 0, stream>>>(
        x, row, eids, offsets,
        We1, be1, We2, be2, Wn11, bn11, Wn12, bn12,
        Wn21, bn21, Wn22, bn22, x_out, N);

    graph_kernel<<<dim3(G), blk, 0, stream>>>(x_out, batch, Wg1, bg1, Wg2, bg2,
                                              (float*)d_out, N, G);
}

// Round 3
// 347.215 us; speedup vs baseline: 7.6840x; 4.5700x over previous
//
#include <hip/hip_runtime.h>
#include <hip/hip_bf16.h>

#define HD 14
#define NOUT 2
#define NN 200000
#define EE 3200000
#define GG 2000

// scan config
#define SBS 256
#define SEL 8
#define CHUNK (SBS*SEL)                 // 2048
#define NB1 ((NN + CHUNK - 1) / CHUNK)  // 98

__device__ __forceinline__ float psi_f(float v) {
    float r = log1pf(fabsf(v));
    return v < 0.f ? -r : r;
}

__device__ __forceinline__ void stage_f(float* dst, const float* src, int n) {
    for (int i = threadIdx.x; i < n; i += blockDim.x) dst[i] = src[i];
}

__device__ __forceinline__ int lower_bound_i(const int* a, int n, int key) {
    int lo = 0, hi = n;
    while (lo < hi) { int mid = (lo + hi) >> 1; if (a[mid] < key) lo = mid + 1; else hi = mid; }
    return lo;
}

// ---- pass 1: per-edge rank within destination node (the only atomic pass) ----
__global__ void __launch_bounds__(256)
rank_kernel(const int* __restrict__ col, int* __restrict__ cnt,
            int* __restrict__ rank, int E)
{
    int e = blockIdx.x * 256 + threadIdx.x;
    if (e >= E) return;
    rank[e] = atomicAdd(&cnt[col[e]], 1);
}

// ---- exclusive scan of cnt[N] -> offsets[N] (3 kernels) ----
__global__ void __launch_bounds__(SBS)
scan1_kernel(const int* __restrict__ cnt, int* __restrict__ excl,
             int* __restrict__ btot, int n)
{
    __shared__ int lds[SBS];
    int tid = threadIdx.x;
    int base = blockIdx.x * CHUNK + tid * SEL;
    int v[SEL]; int s = 0;
    #pragma unroll
    for (int k = 0; k < SEL; ++k) { int i = base + k; v[k] = (i < n) ? cnt[i] : 0; s += v[k]; }
    lds[tid] = s; __syncthreads();
    for (int off = 1; off < SBS; off <<= 1) {
        int t = (tid >= off) ? lds[tid - off] : 0;
        __syncthreads();
        lds[tid] += t;
        __syncthreads();
    }
    int incl = lds[tid];
    int run = incl - s;
    if (tid == SBS - 1) btot[blockIdx.x] = incl;
    #pragma unroll
    for (int k = 0; k < SEL; ++k) { int i = base + k; if (i < n) excl[i] = run; run += v[k]; }
}

__global__ void __launch_bounds__(128)
scan2_kernel(int* __restrict__ btot, int* __restrict__ total_out, int nb)
{
    __shared__ int lds[128];
    int tid = threadIdx.x;
    int v = (tid < nb) ? btot[tid] : 0;
    lds[tid] = v; __syncthreads();
    for (int off = 1; off < 128; off <<= 1) {
        int t = (tid >= off) ? lds[tid - off] : 0;
        __syncthreads();
        lds[tid] += t;
        __syncthreads();
    }
    if (tid < nb) btot[tid] = lds[tid] - v;
    if (tid == 127) *total_out = lds[127];
}

__global__ void __launch_bounds__(SBS)
scan3_kernel(int* __restrict__ excl, const int* __restrict__ btot, int n)
{
    int b = btot[blockIdx.x];
    int base = blockIdx.x * CHUNK + threadIdx.x * SEL;
    #pragma unroll
    for (int k = 0; k < SEL; ++k) { int i = base + k; if (i < n) excl[i] += b; }
}

// ---- BIG PATH pass 2: edge-parallel compute, write message to sorted slot ----
__global__ void __launch_bounds__(256)
edge_compute(const float4* __restrict__ x,
             const int* __restrict__ row, const int* __restrict__ col,
             const int* __restrict__ rank, const int* __restrict__ offsets,
             const float* __restrict__ We1, const float* __restrict__ be1,
             const float* __restrict__ We2, const float* __restrict__ be2,
             const float* __restrict__ Wn11, const float* __restrict__ bn11,
             const float* __restrict__ Wn12, const float* __restrict__ bn12,
             float* __restrict__ m, int E)
{
    __shared__ float sWe1[4*HD], sbe1[HD], sWe2[HD*HD], sbe2[HD];
    __shared__ float sWn11[(1+HD)*HD], sbn11[HD], sWn12[HD*HD], sbn12[HD];
    stage_f(sWe1, We1, 4*HD);        stage_f(sbe1, be1, HD);
    stage_f(sWe2, We2, HD*HD);       stage_f(sbe2, be2, HD);
    stage_f(sWn11, Wn11, (1+HD)*HD); stage_f(sbn11, bn11, HD);
    stage_f(sWn12, Wn12, HD*HD);     stage_f(sbn12, bn12, HD);
    __syncthreads();

    int e = blockIdx.x * 256 + threadIdx.x;
    if (e >= E) return;

    int r = row[e];
    int c = col[e];
    int pos = offsets[c] + rank[e];

    float4 a = x[r];
    float4 b = x[c];

    float f0 = -a.x*a.x + a.y*a.y + a.z*a.z + a.w*a.w;
    float f1 = -a.x*b.x + a.y*b.y + a.z*b.z + a.w*b.w;
    float ipbb = -b.x*b.x + b.y*b.y + b.z*b.z + b.w*b.w;
    float dx = a.x-b.x, dy = a.y-b.y, dz = a.z-b.z, dw = a.w-b.w;
    float f2 = psi_f(ipbb);
    float f3 = psi_f(-dx*dx + dy*dy + dz*dz + dw*dw);

    float h1[HD];
    #pragma unroll
    for (int j = 0; j < HD; ++j) {
        float v = f0*sWe1[0*HD+j] + f1*sWe1[1*HD+j] + f2*sWe1[2*HD+j] + f3*sWe1[3*HD+j] + sbe1[j];
        h1[j] = fmaxf(v, 0.f);
    }
    float ea[HD];
    #pragma unroll
    for (int j = 0; j < HD; ++j) {
        float v = sbe2[j];
        #pragma unroll
        for (int k = 0; k < HD; ++k) v = fmaf(h1[k], sWe2[k*HD+j], v);
        ea[j] = v;
    }
    float h2[HD];
    #pragma unroll
    for (int j = 0; j < HD; ++j) {
        float v = fmaf(f0, sWn11[0*HD+j], sbn11[j]);
        #pragma unroll
        for (int k = 0; k < HD; ++k) v = fmaf(ea[k], sWn11[(1+k)*HD+j], v);
        h2[j] = fmaxf(v, 0.f);
    }
    float mo[HD];
    #pragma unroll
    for (int j = 0; j < HD; ++j) {
        float v = sbn12[j];
        #pragma unroll
        for (int k = 0; k < HD; ++k) v = fmaf(h2[k], sWn12[k*HD+j], v);
        mo[j] = v;
    }

    float4* mp = (float4*)(m + (size_t)pos * 16);
    mp[0] = make_float4(mo[0], mo[1], mo[2], mo[3]);
    mp[1] = make_float4(mo[4], mo[5], mo[6], mo[7]);
    mp[2] = make_float4(mo[8], mo[9], mo[10], mo[11]);
    mp[3] = make_float4(mo[12], mo[13], 0.f, 0.f);
}

// ---- BIG PATH pass 3: contiguous segmented mean + node MLP ----
__global__ void __launch_bounds__(256)
node_agg(const float4* __restrict__ x, const int* __restrict__ offsets,
         const float* __restrict__ m,
         const float* __restrict__ Wn21, const float* __restrict__ bn21,
         const float* __restrict__ Wn22, const float* __restrict__ bn22,
         float* __restrict__ x_out, int N)
{
    __shared__ float sW1[(1+HD)*HD], sb1[HD], sW2[HD*HD], sb2[HD];
    stage_f(sW1, Wn21, (1+HD)*HD); stage_f(sb1, bn21, HD);
    stage_f(sW2, Wn22, HD*HD);     stage_f(sb2, bn22, HD);
    __syncthreads();

    int n = blockIdx.x * 256 + threadIdx.x;
    if (n >= N) return;

    float4 b = x[n];
    float ipbb = -b.x*b.x + b.y*b.y + b.z*b.z + b.w*b.w;

    int lo = offsets[n], hi = offsets[n + 1];
    int deg = hi - lo;

    float agg[HD];
    #pragma unroll
    for (int j = 0; j < HD; ++j) agg[j] = 0.f;

    const float4* mp = (const float4*)(m) + (size_t)lo * 4;
    for (int i = 0; i < deg; ++i) {
        float4 a0 = mp[0], a1 = mp[1], a2 = mp[2], a3 = mp[3];
        mp += 4;
        agg[0] += a0.x;  agg[1] += a0.y;  agg[2] += a0.z;  agg[3] += a0.w;
        agg[4] += a1.x;  agg[5] += a1.y;  agg[6] += a1.z;  agg[7] += a1.w;
        agg[8] += a2.x;  agg[9] += a2.y;  agg[10] += a2.z; agg[11] += a2.w;
        agg[12] += a3.x; agg[13] += a3.y;
    }

    float invc = 1.0f / fmaxf((float)deg, 1.0f);
    #pragma unroll
    for (int j = 0; j < HD; ++j) agg[j] *= invc;

    float h[HD];
    #pragma unroll
    for (int j = 0; j < HD; ++j) {
        float v = fmaf(ipbb, sW1[0*HD+j], sb1[j]);
        #pragma unroll
        for (int k = 0; k < HD; ++k) v = fmaf(agg[k], sW1[(1+k)*HD+j], v);
        h[j] = fmaxf(v, 0.f);
    }
    float xo[16];
    #pragma unroll
    for (int j = 0; j < HD; ++j) {
        float v = sb2[j];
        #pragma unroll
        for (int k = 0; k < HD; ++k) v = fmaf(h[k], sW2[k*HD+j], v);
        xo[j] = v;
    }
    float4* op = (float4*)(x_out + (size_t)n * 16);
    op[0] = make_float4(xo[0], xo[1], xo[2], xo[3]);
    op[1] = make_float4(xo[4], xo[5], xo[6], xo[7]);
    op[2] = make_float4(xo[8], xo[9], xo[10], xo[11]);
    op[3] = make_float4(xo[12], xo[13], 0.f, 0.f);
}

// ---- FALLBACK pass 2: atomic-free scatter of edge ids into col-sorted order ----
__global__ void __launch_bounds__(256)
scatter_kernel(const int* __restrict__ col, const int* __restrict__ rank,
               const int* __restrict__ offsets, int* __restrict__ eids, int E)
{
    int e = blockIdx.x * 256 + threadIdx.x;
    if (e >= E) return;
    eids[offsets[col[e]] + rank[e]] = e;
}

// ---- FALLBACK pass 3: per-node edge recompute + aggregate + node MLP ----
__global__ void __launch_bounds__(256, 4)
node_recompute(const float4* __restrict__ x,
               const int* __restrict__ row, const int* __restrict__ eids,
               const int* __restrict__ offsets,
               const float* __restrict__ We1, const float* __restrict__ be1,
               const float* __restrict__ We2, const float* __restrict__ be2,
               const float* __restrict__ Wn11, const float* __restrict__ bn11,
               const float* __restrict__ Wn12, const float* __restrict__ bn12,
               const float* __restrict__ Wn21, const float* __restrict__ bn21,
               const float* __restrict__ Wn22, const float* __restrict__ bn22,
               float* __restrict__ x_out, int N)
{
    __shared__ float sWe1[4*HD], sbe1[HD], sWe2[HD*HD], sbe2[HD];
    __shared__ float sWn11[(1+HD)*HD], sbn11[HD], sWn12[HD*HD], sbn12[HD];
    __shared__ float sWn21[(1+HD)*HD], sbn21[HD], sWn22[HD*HD], sbn22[HD];
    stage_f(sWe1, We1, 4*HD);        stage_f(sbe1, be1, HD);
    stage_f(sWe2, We2, HD*HD);       stage_f(sbe2, be2, HD);
    stage_f(sWn11, Wn11, (1+HD)*HD); stage_f(sbn11, bn11, HD);
    stage_f(sWn12, Wn12, HD*HD);     stage_f(sbn12, bn12, HD);
    stage_f(sWn21, Wn21, (1+HD)*HD); stage_f(sbn21, bn21, HD);
    stage_f(sWn22, Wn22, HD*HD);     stage_f(sbn22, bn22, HD);
    __syncthreads();

    int n = blockIdx.x * 256 + threadIdx.x;
    if (n >= N) return;

    float4 b = x[n];
    float ipbb = -b.x*b.x + b.y*b.y + b.z*b.z + b.w*b.w;
    float f2 = psi_f(ipbb);

    int lo = offsets[n], hi = offsets[n + 1];
    int deg = hi - lo;

    float agg[HD];
    #pragma unroll
    for (int j = 0; j < HD; ++j) agg[j] = 0.f;

    for (int i = lo; i < hi; ++i) {
        int e = eids[i];
        int r = row[e];
        float4 a = x[r];

        float f0 = -a.x*a.x + a.y*a.y + a.z*a.z + a.w*a.w;
        float f1 = -a.x*b.x + a.y*b.y + a.z*b.z + a.w*b.w;
        float dx = a.x-b.x, dy = a.y-b.y, dz = a.z-b.z, dw = a.w-b.w;
        float f3 = psi_f(-dx*dx + dy*dy + dz*dz + dw*dw);

        float h1[HD];
        #pragma unroll
        for (int j = 0; j < HD; ++j) {
            float v = f0*sWe1[0*HD+j] + f1*sWe1[1*HD+j] + f2*sWe1[2*HD+j] + f3*sWe1[3*HD+j] + sbe1[j];
            h1[j] = fmaxf(v, 0.f);
        }
        float ea[HD];
        #pragma unroll
        for (int j = 0; j < HD; ++j) {
            float v = sbe2[j];
            #pragma unroll
            for (int k = 0; k < HD; ++k) v = fmaf(h1[k], sWe2[k*HD+j], v);
            ea[j] = v;
        }
        float h2[HD];
        #pragma unroll
        for (int j = 0; j < HD; ++j) {
            float v = fmaf(f0, sWn11[0*HD+j], sbn11[j]);
            #pragma unroll
            for (int k = 0; k < HD; ++k) v = fmaf(ea[k], sWn11[(1+k)*HD+j], v);
            h2[j] = fmaxf(v, 0.f);
        }
        #pragma unroll
        for (int j = 0; j < HD; ++j) {
            float v = sbn12[j];
            #pragma unroll
            for (int k = 0; k < HD; ++k) v = fmaf(h2[k], sWn12[k*HD+j], v);
            agg[j] += v;
        }
    }

    float invc = 1.0f / fmaxf((float)deg, 1.0f);
    #pragma unroll
    for (int j = 0; j < HD; ++j) agg[j] *= invc;

    float h[HD];
    #pragma unroll
    for (int j = 0; j < HD; ++j) {
        float v = fmaf(ipbb, sWn21[0*HD+j], sbn21[j]);
        #pragma unroll
        for (int k = 0; k < HD; ++k) v = fmaf(agg[k], sWn21[(1+k)*HD+j], v);
        h[j] = fmaxf(v, 0.f);
    }
    float xo[16];
    #pragma unroll
    for (int j = 0; j < HD; ++j) {
        float v = sbn22[j];
        #pragma unroll
        for (int k = 0; k < HD; ++k) v = fmaf(h[k], sWn22[k*HD+j], v);
        xo[j] = v;
    }
    float4* op = (float4*)(x_out + (size_t)n * 16);
    op[0] = make_float4(xo[0], xo[1], xo[2], xo[3]);
    op[1] = make_float4(xo[4], xo[5], xo[6], xo[7]);
    op[2] = make_float4(xo[8], xo[9], xo[10], xo[11]);
    op[3] = make_float4(xo[12], xo[13], 0.f, 0.f);
}

// ---- pass 4: per-graph mean (batch sorted -> contiguous ranges) + global MLP ----
__global__ void __launch_bounds__(256)
graph_kernel(const float* __restrict__ x_out, const int* __restrict__ batch,
             const float* __restrict__ Wg1, const float* __restrict__ bg1,
             const float* __restrict__ Wg2, const float* __restrict__ bg2,
             float* __restrict__ out, int N, int G)
{
    __shared__ float red[256 * 15];
    int g = blockIdx.x;
    int tid = threadIdx.x;

    int lo = lower_bound_i(batch, N, g);
    int hi = lower_bound_i(batch, N, g + 1);

    float acc[HD];
    #pragma unroll
    for (int j = 0; j < HD; ++j) acc[j] = 0.f;

    for (int n = lo + tid; n < hi; n += 256) {
        const float* xp = x_out + (size_t)n * 16;
        #pragma unroll
        for (int j = 0; j < HD; ++j) acc[j] += xp[j];
    }
    #pragma unroll
    for (int j = 0; j < HD; ++j) red[tid * 15 + j] = acc[j];
    __syncthreads();

    for (int s = 128; s >= 1; s >>= 1) {
        if (tid < s) {
            #pragma unroll
            for (int j = 0; j < HD; ++j) red[tid * 15 + j] += red[(tid + s) * 15 + j];
        }
        __syncthreads();
    }

    if (tid == 0) {
        float invc = 1.0f / fmaxf((float)(hi - lo), 1.0f);
        float gm[HD];
        #pragma unroll
        for (int j = 0; j < HD; ++j) gm[j] = red[j] * invc;
        float h[HD];
        #pragma unroll
        for (int j = 0; j < HD; ++j) {
            float v = bg1[j];
            #pragma unroll
            for (int k = 0; k < HD; ++k) v = fmaf(gm[k], Wg1[k*HD+j], v);
            h[j] = fmaxf(v, 0.f);
        }
        #pragma unroll
        for (int o = 0; o < NOUT; ++o) {
            float v = bg2[o];
            #pragma unroll
            for (int k = 0; k < HD; ++k) v = fmaf(h[k], Wg2[k*NOUT+o], v);
            out[g * NOUT + o] = v;
        }
    }
}

extern "C" void kernel_launch(void* const* d_in, const int* in_sizes, int n_in,
                              void* d_out, int out_size, void* d_ws, size_t ws_size,
                              hipStream_t stream) {
    const int N = NN, E = EE, G = GG;

    const float4* x     = (const float4*)d_in[0];
    const int*    eidx  = (const int*)d_in[1];
    const int*    batch = (const int*)d_in[2];
    const float*  We1  = (const float*)d_in[3];
    const float*  be1  = (const float*)d_in[4];
    const float*  We2  = (const float*)d_in[5];
    const float*  be2  = (const float*)d_in[6];
    const float*  Wn11 = (const float*)d_in[7];
    const float*  bn11 = (const float*)d_in[8];
    const float*  Wn12 = (const float*)d_in[9];
    const float*  bn12 = (const float*)d_in[10];
    const float*  Wn21 = (const float*)d_in[11];
    const float*  bn21 = (const float*)d_in[12];
    const float*  Wn22 = (const float*)d_in[13];
    const float*  bn22 = (const float*)d_in[14];
    const float*  Wg1  = (const float*)d_in[15];
    const float*  bg1  = (const float*)d_in[16];
    const float*  Wg2  = (const float*)d_in[17];
    const float*  bg2  = (const float*)d_in[18];

    const int* row = eidx;
    const int* col = eidx + E;

    dim3 blk(256);
    const size_t NEED_BIG = 234377216;   // layout below

    if (ws_size >= NEED_BIG) {
        // BIG path layout (bytes):
        //   cnt     @ 0          (800000)
        //   rank    @ 1048576    (12.8MB)
        //   offsets @ 14000128   (800004)
        //   btot    @ 14800384   (512)
        //   m       @ 16777216   (E*16*4 = 204800000)
        //   x_out   @ 221577216  (N*16*4 = 12800000)  -> ends 234377216
        char* ws = (char*)d_ws;
        int*   cnt     = (int*)(ws + 0);
        int*   rank    = (int*)(ws + 1048576);
        int*   offsets = (int*)(ws + 14000128);
        int*   btot    = (int*)(ws + 14800384);
        float* m       = (float*)(ws + 16777216);
        float* x_out   = (float*)(ws + 221577216);

        hipMemsetAsync(cnt, 0, (size_t)N * sizeof(int), stream);

        rank_kernel<<<dim3((E + 255) / 256), blk, 0, stream>>>(col, cnt, rank, E);
        scan1_kernel<<<dim3(NB1), dim3(SBS), 0, stream>>>(cnt, offsets, btot, N);
        scan2_kernel<<<dim3(1), dim3(128), 0, stream>>>(btot, offsets + N, NB1);
        scan3_kernel<<<dim3(NB1), dim3(SBS), 0, stream>>>(offsets, btot, N);

        edge_compute<<<dim3((E + 255) / 256), blk, 0, stream>>>(
            x, row, col, rank, offsets,
            We1, be1, We2, be2, Wn11, bn11, Wn12, bn12, m, E);

        node_agg<<<dim3((N + 255) / 256), blk, 0, stream>>>(
            x, offsets, m, Wn21, bn21, Wn22, bn22, x_out, N);

        graph_kernel<<<dim3(G), blk, 0, stream>>>(x_out, batch, Wg1, bg1, Wg2, bg2,
                                                  (float*)d_out, N, G);
    } else {
        // FALLBACK (round-2 proven path)
        char* ws = (char*)d_ws;
        int*   cnt     = (int*)(ws + 0);
        int*   rank    = (int*)(ws + 800000);
        int*   offsets = (int*)(ws + 13600000);
        int*   btot    = (int*)(ws + 14400256);
        int*   eids    = (int*)(ws + 14400768);
        float* x_out   = (float*)(ws + 27200768);

        hipMemsetAsync(cnt, 0, (size_t)N * sizeof(int), stream);

        rank_kernel<<<dim3((E + 255) / 256), blk, 0, stream>>>(col, cnt, rank, E);
        scan1_kernel<<<dim3(NB1), dim3(SBS), 0, stream>>>(cnt, offsets, btot, N);
        scan2_kernel<<<dim3(1), dim3(128), 0, stream>>>(btot, offsets + N, NB1);
        scan3_kernel<<<dim3(NB1), dim3(SBS), 0, stream>>>(offsets, btot, N);
        scatter_kernel<<<dim3((E + 255) / 256), blk, 0, stream>>>(col, rank, offsets, eids, E);

        node_recompute<<<dim3((N + 255) / 256), blk, 0, stream>>>(
            x, row, eids, offsets,
            We1, be1, We2, be2, Wn11, bn11, Wn12, bn12,
            Wn21, bn21, Wn22, bn22, x_out, N);

        graph_kernel<<<dim3(G), blk, 0, stream>>>(x_out, batch, Wg1, bg1, Wg2, bg2,
                                                  (float*)d_out, N, G);
    }
}

// Round 4
// 306.150 us; speedup vs baseline: 8.7147x; 1.1341x over previous
//
#include <hip/hip_runtime.h>
#include <hip/hip_fp16.h>

#define HD 14
#define NOUT 2
#define NN 200000
#define EE 3200000
#define GG 2000

// scan config
#define SBS 256
#define SEL 8
#define CHUNK (SBS*SEL)                 // 2048
#define NB1 ((NN + CHUNK - 1) / CHUNK)  // 98

__device__ __forceinline__ float psi_f(float v) {
    float r = log1pf(fabsf(v));
    return v < 0.f ? -r : r;
}

__device__ __forceinline__ int lower_bound_i(const int* a, int n, int key) {
    int lo = 0, hi = n;
    while (lo < hi) { int mid = (lo + hi) >> 1; if (a[mid] < key) lo = mid + 1; else hi = mid; }
    return lo;
}

// ---- pass 0: fold We2 into Wn11 (both are applied linearly back-to-back) ----
// C[k][j] = sum_t We2[k][t] * Wn11[1+t][j];  bp[j] = bn11[j] + sum_t be2[t]*Wn11[1+t][j]
__global__ void __launch_bounds__(256)
fold_kernel(const float* __restrict__ We2, const float* __restrict__ be2,
            const float* __restrict__ Wn11, const float* __restrict__ bn11,
            float* __restrict__ C, float* __restrict__ bp)
{
    int t = threadIdx.x;
    if (t < HD*HD) {
        int k = t / HD, j = t % HD;
        float s = 0.f;
        #pragma unroll
        for (int u = 0; u < HD; ++u) s = fmaf(We2[k*HD+u], Wn11[(1+u)*HD+j], s);
        C[t] = s;
    } else if (t < HD*HD + HD) {
        int j = t - HD*HD;
        float s = bn11[j];
        #pragma unroll
        for (int u = 0; u < HD; ++u) s = fmaf(be2[u], Wn11[(1+u)*HD+j], s);
        bp[j] = s;
    }
}

// ---- pass 1: per-edge rank within destination node (the only atomic pass) ----
__global__ void __launch_bounds__(256)
rank_kernel(const int* __restrict__ col, int* __restrict__ cnt,
            int* __restrict__ rank, int E)
{
    int e = blockIdx.x * 256 + threadIdx.x;
    if (e >= E) return;
    rank[e] = atomicAdd(&cnt[col[e]], 1);
}

// ---- scan (2 kernels; block bases folded into consumers) ----
__global__ void __launch_bounds__(SBS)
scan1_kernel(const int* __restrict__ cnt, int* __restrict__ excl,
             int* __restrict__ btot, int n)
{
    __shared__ int lds[SBS];
    int tid = threadIdx.x;
    int base = blockIdx.x * CHUNK + tid * SEL;
    int v[SEL]; int s = 0;
    #pragma unroll
    for (int k = 0; k < SEL; ++k) { int i = base + k; v[k] = (i < n) ? cnt[i] : 0; s += v[k]; }
    lds[tid] = s; __syncthreads();
    for (int off = 1; off < SBS; off <<= 1) {
        int t = (tid >= off) ? lds[tid - off] : 0;
        __syncthreads();
        lds[tid] += t;
        __syncthreads();
    }
    int incl = lds[tid];
    int run = incl - s;                       // chunk-local exclusive base
    if (tid == SBS - 1) btot[blockIdx.x] = incl;
    #pragma unroll
    for (int k = 0; k < SEL; ++k) { int i = base + k; if (i < n) excl[i] = run; run += v[k]; }
}

__global__ void __launch_bounds__(128)
scan2_kernel(int* __restrict__ btot, int* __restrict__ spare, int nb)
{
    __shared__ int lds[128];
    int tid = threadIdx.x;
    int v = (tid < nb) ? btot[tid] : 0;
    lds[tid] = v; __syncthreads();
    for (int off = 1; off < 128; off <<= 1) {
        int t = (tid >= off) ? lds[tid - off] : 0;
        __syncthreads();
        lds[tid] += t;
        __syncthreads();
    }
    if (tid < nb) btot[tid] = lds[tid] - v;   // exclusive chunk bases, in place
    if (tid == 127) *spare = lds[127];
}

// ---- pass 2: edge-parallel compute (folded MLP), f16 message to sorted slot ----
__global__ void __launch_bounds__(256)
edge_compute(const float4* __restrict__ x,
             const int* __restrict__ row, const int* __restrict__ col,
             const int* __restrict__ rank, const int* __restrict__ excl,
             const int* __restrict__ btot,
             const float* __restrict__ We1, const float* __restrict__ be1,
             const float* __restrict__ Wn11,   // row 0 used
             const float* __restrict__ C, const float* __restrict__ bp,
             __half* __restrict__ m, int E)
{
    int e = blockIdx.x * 256 + threadIdx.x;
    if (e >= E) return;

    int r = row[e];
    int c = col[e];
    int pos = excl[c] + btot[c >> 11] + rank[e];

    float4 a = x[r];
    float4 b = x[c];

    float f0 = -a.x*a.x + a.y*a.y + a.z*a.z + a.w*a.w;          // ip(src,src)
    float f1 = -a.x*b.x + a.y*b.y + a.z*b.z + a.w*b.w;          // ip(src,dst)
    float ipbb = -b.x*b.x + b.y*b.y + b.z*b.z + b.w*b.w;
    float dx = a.x-b.x, dy = a.y-b.y, dz = a.z-b.z, dw = a.w-b.w;
    float f2 = psi_f(ipbb);
    float f3 = psi_f(-dx*dx + dy*dy + dz*dz + dw*dw);

    float h1[HD];
    #pragma unroll
    for (int j = 0; j < HD; ++j) {
        float v = f0*We1[j] + f1*We1[HD+j] + f2*We1[2*HD+j] + f3*We1[3*HD+j] + be1[j];
        h1[j] = fmaxf(v, 0.f);
    }

    __align__(16) __half hv[16];
    #pragma unroll
    for (int j = 0; j < HD; ++j) {
        float v = fmaf(f0, Wn11[j], bp[j]);
        #pragma unroll
        for (int k = 0; k < HD; ++k) v = fmaf(h1[k], C[k*HD+j], v);
        hv[j] = __float2half_rn(fmaxf(v, 0.f));   // h2
    }
    hv[14] = __float2half_rn(0.f);
    hv[15] = __float2half_rn(0.f);

    uint4* mp = (uint4*)(m + (size_t)pos * 16);
    mp[0] = *reinterpret_cast<uint4*>(hv);
    mp[1] = *reinterpret_cast<uint4*>(hv + 8);
}

// ---- pass 3: contiguous segmented sum of h2 + Wn12 once per node + node MLP ----
__global__ void __launch_bounds__(256)
node_agg(const float4* __restrict__ x,
         const int* __restrict__ excl, const int* __restrict__ btot,
         const __half* __restrict__ m,
         const float* __restrict__ Wn12, const float* __restrict__ bn12,
         const float* __restrict__ Wn21, const float* __restrict__ bn21,
         const float* __restrict__ Wn22, const float* __restrict__ bn22,
         float* __restrict__ x_out, int N, int E)
{
    int n = blockIdx.x * 256 + threadIdx.x;
    if (n >= N) return;

    float4 b = x[n];
    float ipbb = -b.x*b.x + b.y*b.y + b.z*b.z + b.w*b.w;

    int lo = excl[n] + btot[n >> 11];
    int hi = (n + 1 < N) ? (excl[n+1] + btot[(n+1) >> 11]) : E;
    int deg = hi - lo;

    float agg[HD];
    #pragma unroll
    for (int j = 0; j < HD; ++j) agg[j] = 0.f;

    const uint4* mp = (const uint4*)(m + (size_t)lo * 16);
    for (int i = 0; i < deg; ++i) {
        uint4 q0 = mp[0];
        uint4 q1 = mp[1];
        mp += 2;
        const __half* h0 = reinterpret_cast<const __half*>(&q0);
        const __half* h1p = reinterpret_cast<const __half*>(&q1);
        #pragma unroll
        for (int j = 0; j < 8; ++j) agg[j] += __half2float(h0[j]);
        #pragma unroll
        for (int j = 0; j < 6; ++j) agg[8+j] += __half2float(h1p[j]);
    }

    float aggm[HD];
    if (deg > 0) {
        float inv = 1.0f / (float)deg;
        #pragma unroll
        for (int k = 0; k < HD; ++k) agg[k] *= inv;
        #pragma unroll
        for (int j = 0; j < HD; ++j) {
            float v = bn12[j];
            #pragma unroll
            for (int k = 0; k < HD; ++k) v = fmaf(agg[k], Wn12[k*HD+j], v);
            aggm[j] = v;
        }
    } else {
        #pragma unroll
        for (int j = 0; j < HD; ++j) aggm[j] = 0.f;
    }

    float h[HD];
    #pragma unroll
    for (int j = 0; j < HD; ++j) {
        float v = fmaf(ipbb, Wn21[j], bn21[j]);
        #pragma unroll
        for (int k = 0; k < HD; ++k) v = fmaf(aggm[k], Wn21[(1+k)*HD+j], v);
        h[j] = fmaxf(v, 0.f);
    }
    float xo[16];
    #pragma unroll
    for (int j = 0; j < HD; ++j) {
        float v = bn22[j];
        #pragma unroll
        for (int k = 0; k < HD; ++k) v = fmaf(h[k], Wn22[k*HD+j], v);
        xo[j] = v;
    }
    float4* op = (float4*)(x_out + (size_t)n * 16);
    op[0] = make_float4(xo[0], xo[1], xo[2], xo[3]);
    op[1] = make_float4(xo[4], xo[5], xo[6], xo[7]);
    op[2] = make_float4(xo[8], xo[9], xo[10], xo[11]);
    op[3] = make_float4(xo[12], xo[13], 0.f, 0.f);
}

// ---- pass 4: per-graph mean (batch sorted -> contiguous ranges) + global MLP ----
__global__ void __launch_bounds__(256)
graph_kernel(const float* __restrict__ x_out, const int* __restrict__ batch,
             const float* __restrict__ Wg1, const float* __restrict__ bg1,
             const float* __restrict__ Wg2, const float* __restrict__ bg2,
             float* __restrict__ out, int N, int G)
{
    __shared__ float red[256 * 15];
    int g = blockIdx.x;
    int tid = threadIdx.x;

    int lo = lower_bound_i(batch, N, g);
    int hi = lower_bound_i(batch, N, g + 1);

    float acc[HD];
    #pragma unroll
    for (int j = 0; j < HD; ++j) acc[j] = 0.f;

    for (int n = lo + tid; n < hi; n += 256) {
        const float* xp = x_out + (size_t)n * 16;
        #pragma unroll
        for (int j = 0; j < HD; ++j) acc[j] += xp[j];
    }
    #pragma unroll
    for (int j = 0; j < HD; ++j) red[tid * 15 + j] = acc[j];
    __syncthreads();

    for (int s = 128; s >= 1; s >>= 1) {
        if (tid < s) {
            #pragma unroll
            for (int j = 0; j < HD; ++j) red[tid * 15 + j] += red[(tid + s) * 15 + j];
        }
        __syncthreads();
    }

    if (tid == 0) {
        float invc = 1.0f / fmaxf((float)(hi - lo), 1.0f);
        float gm[HD];
        #pragma unroll
        for (int j = 0; j < HD; ++j) gm[j] = red[j] * invc;
        float h[HD];
        #pragma unroll
        for (int j = 0; j < HD; ++j) {
            float v = bg1[j];
            #pragma unroll
            for (int k = 0; k < HD; ++k) v = fmaf(gm[k], Wg1[k*HD+j], v);
            h[j] = fmaxf(v, 0.f);
        }
        #pragma unroll
        for (int o = 0; o < NOUT; ++o) {
            float v = bg2[o];
            #pragma unroll
            for (int k = 0; k < HD; ++k) v = fmaf(h[k], Wg2[k*NOUT+o], v);
            out[g * NOUT + o] = v;
        }
    }
}

extern "C" void kernel_launch(void* const* d_in, const int* in_sizes, int n_in,
                              void* d_out, int out_size, void* d_ws, size_t ws_size,
                              hipStream_t stream) {
    const int N = NN, E = EE, G = GG;

    const float4* x     = (const float4*)d_in[0];
    const int*    eidx  = (const int*)d_in[1];
    const int*    batch = (const int*)d_in[2];
    const float*  We1  = (const float*)d_in[3];
    const float*  be1  = (const float*)d_in[4];
    const float*  We2  = (const float*)d_in[5];
    const float*  be2  = (const float*)d_in[6];
    const float*  Wn11 = (const float*)d_in[7];
    const float*  bn11 = (const float*)d_in[8];
    const float*  Wn12 = (const float*)d_in[9];
    const float*  bn12 = (const float*)d_in[10];
    const float*  Wn21 = (const float*)d_in[11];
    const float*  bn21 = (const float*)d_in[12];
    const float*  Wn22 = (const float*)d_in[13];
    const float*  bn22 = (const float*)d_in[14];
    const float*  Wg1  = (const float*)d_in[15];
    const float*  bg1  = (const float*)d_in[16];
    const float*  Wg2  = (const float*)d_in[17];
    const float*  bg2  = (const float*)d_in[18];

    const int* row = eidx;       // edge_index[0]
    const int* col = eidx + E;   // edge_index[1]

    // workspace layout (bytes):
    //   cnt   @ 0          (800000)   zeroed
    //   rank  @ 1048576    (12.8MB)
    //   excl  @ 14000128   (800000)
    //   btot  @ 14800384   (512)
    //   spare @ 14800896   (4)
    //   Cfold @ 14801152   (784)
    //   bfold @ 14802176   (56)
    //   m     @ 16777216   (E*16 halves = 102400000) -> ends 119177216
    //   x_out @ 119177216  (N*16 floats = 12800000)  -> ends 131977216
    char*   ws    = (char*)d_ws;
    int*    cnt   = (int*)(ws + 0);
    int*    rank  = (int*)(ws + 1048576);
    int*    excl  = (int*)(ws + 14000128);
    int*    btot  = (int*)(ws + 14800384);
    int*    spare = (int*)(ws + 14800896);
    float*  Cfold = (float*)(ws + 14801152);
    float*  bfold = (float*)(ws + 14802176);
    __half* m     = (__half*)(ws + 16777216);
    float*  x_out = (float*)(ws + 119177216);

    hipMemsetAsync(cnt, 0, (size_t)N * sizeof(int), stream);

    dim3 blk(256);
    fold_kernel<<<dim3(1), blk, 0, stream>>>(We2, be2, Wn11, bn11, Cfold, bfold);

    rank_kernel<<<dim3((E + 255) / 256), blk, 0, stream>>>(col, cnt, rank, E);
    scan1_kernel<<<dim3(NB1), dim3(SBS), 0, stream>>>(cnt, excl, btot, N);
    scan2_kernel<<<dim3(1), dim3(128), 0, stream>>>(btot, spare, NB1);

    edge_compute<<<dim3((E + 255) / 256), blk, 0, stream>>>(
        x, row, col, rank, excl, btot,
        We1, be1, Wn11, Cfold, bfold, m, E);

    node_agg<<<dim3((N + 255) / 256), blk, 0, stream>>>(
        x, excl, btot, m, Wn12, bn12, Wn21, bn21, Wn22, bn22, x_out, N, E);

    graph_kernel<<<dim3(G), blk, 0, stream>>>(x_out, batch, Wg1, bg1, Wg2, bg2,
                                              (float*)d_out, N, G);
}